// Round 5
// baseline (304.972 us; speedup 1.0000x reference)
//
#include <hip/hip_runtime.h>
#include <hip/hip_bf16.h>

// Embedding gather: token_ids [8,4096] int32, embedding_matrix [50257,1024] f32
// -> out [8,4096,1024] f32.  Pure memory-bound row copy.
//
// R4 (re-run of R3; previous attempt hit GPU acquisition timeout):
// Native clang vector type (ext_vector_type) so __builtin_nontemporal_store
// accepts the pointer (HIP's float4 is a class and is rejected).
// 8 rows per block. Prefetch 8 wave-uniform ids (scalar loads), then issue
// 8 independent 16B/lane row loads (8 KiB in flight per wave) before storing.
// Non-temporal stores keep the write-once output stream from evicting the
// ~200 MB embedding table out of L3 (256 MB).

#define DIM 1024
#define F4_PER_ROW (DIM / 4)     // 256 16B-chunks per row
#define ROWS_PER_BLOCK 8

typedef float v4f __attribute__((ext_vector_type(4)));

__global__ __launch_bounds__(256) void embed_gather_kernel(
        const int* __restrict__ ids,
        const float* __restrict__ emb,
        float* __restrict__ out,
        int n_tokens) {
    const int tid  = threadIdx.x;
    const int base = blockIdx.x * ROWS_PER_BLOCK;

    const v4f* __restrict__ emb4 = reinterpret_cast<const v4f*>(emb);
    v4f* __restrict__ out4       = reinterpret_cast<v4f*>(out);

    if (base + ROWS_PER_BLOCK <= n_tokens) {
        // Fast path: full 8-row block.
        int id[ROWS_PER_BLOCK];
#pragma unroll
        for (int r = 0; r < ROWS_PER_BLOCK; ++r)
            id[r] = ids[base + r];              // wave-uniform -> s_load

        v4f v[ROWS_PER_BLOCK];
#pragma unroll
        for (int r = 0; r < ROWS_PER_BLOCK; ++r)
            v[r] = emb4[(size_t)id[r] * F4_PER_ROW + tid];   // 8 loads in flight

#pragma unroll
        for (int r = 0; r < ROWS_PER_BLOCK; ++r)
            __builtin_nontemporal_store(
                v[r], &out4[(size_t)(base + r) * F4_PER_ROW + tid]);
    } else {
        // Tail (not hit for 32768 tokens, kept for safety).
        for (int r = 0; r < ROWS_PER_BLOCK; ++r) {
            int tok = base + r;
            if (tok >= n_tokens) break;
            int id = ids[tok];
            v4f v = emb4[(size_t)id * F4_PER_ROW + tid];
            __builtin_nontemporal_store(v, &out4[(size_t)tok * F4_PER_ROW + tid]);
        }
    }
}

extern "C" void kernel_launch(void* const* d_in, const int* in_sizes, int n_in,
                              void* d_out, int out_size, void* d_ws, size_t ws_size,
                              hipStream_t stream) {
    const int*   ids = (const int*)d_in[0];     // 8*4096 token ids
    const float* emb = (const float*)d_in[1];   // 50257*1024 embedding
    float*       out = (float*)d_out;           // 8*4096*1024

    const int n_tokens = in_sizes[0];           // 32768
    const int n_blocks = (n_tokens + ROWS_PER_BLOCK - 1) / ROWS_PER_BLOCK;
    embed_gather_kernel<<<dim3(n_blocks), dim3(256), 0, stream>>>(ids, emb, out, n_tokens);
}